// Round 7
// baseline (14184.105 us; speedup 1.0000x reference)
//
#include <hip/hip_runtime.h>

// Problem constants (fixed by reference setup)
#define B_ 32
#define T_ 8192
#define I_ 16
#define H_ 128
#define P_ 1024
#define O_ 3
#define NB 4                 // batches per block
#define BLOCKS (B_ / NB)     // 8

typedef _Float16 h4v __attribute__((ext_vector_type(4)));
typedef _Float16 h8v __attribute__((ext_vector_type(8)));
typedef float f4v __attribute__((ext_vector_type(4)));

// xor16 via ds_swizzle (proven 0x401F), xor32 via gfx950 permlane32_swap.
#define SWZF(v, imm) \
    __int_as_float(__builtin_amdgcn_ds_swizzle(__float_as_int(v), (imm)))
__device__ __forceinline__ float xor32_add(float p) {
    float a = p, b = p;
    asm("v_permlane32_swap_b32 %0, %1" : "+v"(a), "+v"(b));
    return a + b;
}

__device__ __forceinline__ float sigf(float x) {
    return 1.f / (1.f + __expf(-x));
}
__device__ __forceinline__ float tanh_f(float x) {
    return 2.f / (1.f + __expf(-2.f * x)) - 1.f;
}
__device__ __forceinline__ h4v cvt4(float4 v) {
    return (h4v){(_Float16)v.x, (_Float16)v.y, (_Float16)v.z, (_Float16)v.w};
}
// LDS-only barrier (x-prefetch global loads consumed via register dep).
__device__ __forceinline__ void lds_barrier() {
    asm volatile("s_waitcnt lgkmcnt(0)\n\ts_barrier" ::: "memory");
}

// R12: MFMA recurrence. R7/R10/R11 linear system => v_dot2 ~6cy, fma_mix
// ~6cy, plain VALU 2cy, fixed ~440cy: the dot phase (864cy) dominates and
// no VALU dtype escapes quarter-rate VOP3P. Matrix core replaces it:
// gates[512x4batch] = W[512x144] x [h;x][144x4] via 20 mfma_16x16x32_f16
// per wave per step (~120cy). Wave w owns units [16w,16w+16) for ALL 4
// gates (M-tiles {w,w+8,w+16,w+24}) so i,f,g,o combine in-lane.
// A-frags (weights) persistent in VGPRs; bias = MFMA C-init; K-tile 4 is
// W_ih zero-padded to 32. H double-buffered in LDS [16][128] f16 with +8n
// column rotation (b64 write / b128 read, bank-spread). C layout (m89):
// col=lane&15 (batch), row=(lane>>4)*4+reg (unit j0+r). Lanes with
// col>=NB compute a finite phantom batch (zero-init H) - discarded.
// Sums/counts: proven per-batch LDS arrays + 1-step-pipelined atomics;
// single lds_barrier per step.
__global__ __launch_bounds__(512, 2)
void lstm_fused(
    const float* __restrict__ x,      // [B,T,16]
    const float* __restrict__ W_ih,   // [512,16]
    const float* __restrict__ W_hh,   // [512,128]
    const float* __restrict__ b_ih,   // [512]
    const float* __restrict__ b_hh,   // [512]
    const float* __restrict__ W_fc,   // [3,128]
    float* __restrict__ sums,         // [B,P,3]  (fully overwritten per block)
    float* __restrict__ counts)       // [B,P]    (fully overwritten per block)
{
    const int bx   = blockIdx.x;
    const int tid  = threadIdx.x;
    const int w    = tid >> 6;        // wave 0..7: units [16w, 16w+16)
    const int lane = tid & 63;
    const int n    = lane & 15;       // batch column (valid if < NB)
    const int gh   = lane >> 4;       // k-group / C-row group
    const int j0   = 16 * w + 4 * gh; // first unit of this lane's C rows

    __shared__ float sums_lds[NB][P_ * O_];            // 48 KB
    __shared__ float counts_lds[NB][P_];               // 16 KB
    __shared__ __align__(16) _Float16 Hlds[2][16][H_]; // 8 KB (rows>=NB phantom)
    __shared__ __align__(16) _Float16 xt[2][16][NB][I_]; // 4 KB

    // ---- A fragments (weights), persistent: A[row = lane&15][k = gh*8+i] ----
    h8v A[4][5];
    #pragma unroll
    for (int G = 0; G < 4; ++G) {
        const int row = 128 * G + 16 * w + n;          // W row (A-layout: lane&15)
        const float* wr = W_hh + (size_t)row * H_;
        #pragma unroll
        for (int kt = 0; kt < 4; ++kt) {
            h8v f;
            #pragma unroll
            for (int i = 0; i < 8; ++i)
                f[i] = (_Float16)wr[32 * kt + 8 * gh + i];
            A[G][kt] = f;
        }
        h8v fx = (h8v){(_Float16)0.f, (_Float16)0.f, (_Float16)0.f, (_Float16)0.f,
                       (_Float16)0.f, (_Float16)0.f, (_Float16)0.f, (_Float16)0.f};
        if (gh < 2) {                                  // k 0..15 = x, 16..31 = pad
            #pragma unroll
            for (int i = 0; i < 8; ++i)
                fx[i] = (_Float16)W_ih[(size_t)row * I_ + 8 * gh + i];
        }
        A[G][4] = fx;
    }

    // bias as MFMA C-init (C rows j0+r, column-independent)
    f4v biasv[4];
    #pragma unroll
    for (int G = 0; G < 4; ++G) {
        f4v bv;
        #pragma unroll
        for (int r = 0; r < 4; ++r)
            bv[r] = b_ih[128 * G + j0 + r] + b_hh[128 * G + j0 + r];
        biasv[G] = bv;
    }

    // FC weights for this lane's 4 units
    float wfc0[4], wfc1[4], wfc2[4];
    #pragma unroll
    for (int r = 0; r < 4; ++r) {
        wfc0[r] = W_fc[0 * H_ + j0 + r];
        wfc1[r] = W_fc[1 * H_ + j0 + r];
        wfc2[r] = W_fc[2 * H_ + j0 + r];
    }

    // ---- init LDS ----
    for (int i = tid; i < NB * P_ * O_; i += 512) ((float*)sums_lds)[i] = 0.f;
    for (int i = tid; i < NB * P_;      i += 512) ((float*)counts_lds)[i] = 0.f;
    for (int i = tid; i < 2 * 16 * H_;  i += 512) ((_Float16*)Hlds)[i] = (_Float16)0.f;

    // ---- x prefetch: waves 0-3 stage 16-step tiles for the 4 batches ----
    const int pb = (tid >> 6) & 3;    // batch (tid<256 only)
    const int r6 = tid & 63;
    const int ps = r6 >> 2;           // step within tile
    const int pe = r6 & 3;            // float4 group
    const float* xb_pb = x + (size_t)(NB * bx + pb) * T_ * I_;
    float4 xr4 = make_float4(0.f, 0.f, 0.f, 0.f);
    if (tid < 256) {
        xr4 = *(const float4*)&xb_pb[ps * I_ + pe * 4];
        *(h4v*)&xt[0][ps][pb][pe * 4] = cvt4(xr4);
    }

    float cc[4] = {0.f, 0.f, 0.f, 0.f};   // cell state (unit j0+r, batch n)
    float pp0 = 0.f, pp1 = 0.f, pp2 = 0.f;
    int pid = P_;
    __syncthreads();

    #pragma unroll 1
    for (int t = 0; t < T_; ++t) {
        const int off = t & 15;
        const int btx = (t >> 4) & 1;
        const int par = t & 1;

        // pipelined sums/counts atomics from step t-1 (complete during MFMA)
        if (t != 0 && lane < NB && (unsigned)pid < (unsigned)P_) {
            atomicAdd(&sums_lds[lane][pid * O_ + 0], pp0);
            atomicAdd(&sums_lds[lane][pid * O_ + 1], pp1);
            atomicAdd(&sums_lds[lane][pid * O_ + 2], pp2);
            if (w == 0) atomicAdd(&counts_lds[lane][pid], 1.f);
        }

        // x prefetch: issue tile t+16 at off==0, commit at off==8
        if (tid < 256) {
            if (off == 0 && t + 16 < T_)
                xr4 = *(const float4*)&xb_pb[(t + 16 + ps) * I_ + pe * 4];
            if (off == 8 && t + 8 < T_)
                *(h4v*)&xt[btx ^ 1][ps][pb][pe * 4] = cvt4(xr4);
        }

        // B fragments: B[k][col=n], k = 32kt + 8gh + i; H rotated by +8n
        h8v Bf0 = *(const h8v*)&Hlds[par][n][(  0 + 8 * gh + 8 * n) & 127];
        h8v Bf1 = *(const h8v*)&Hlds[par][n][( 32 + 8 * gh + 8 * n) & 127];
        h8v Bf2 = *(const h8v*)&Hlds[par][n][( 64 + 8 * gh + 8 * n) & 127];
        h8v Bf3 = *(const h8v*)&Hlds[par][n][( 96 + 8 * gh + 8 * n) & 127];
        h8v bxf = (h8v){(_Float16)0.f, (_Float16)0.f, (_Float16)0.f, (_Float16)0.f,
                        (_Float16)0.f, (_Float16)0.f, (_Float16)0.f, (_Float16)0.f};
        if (gh < 2)                       // x rows (k 128..143); pad rows zero
            bxf = *(const h8v*)&xt[btx][off][n & 3][gh * 8];
        const int idn = (int)(float)xt[btx][off][n & 3][2];   // exact (id<2048)

        // ---- 20 MFMA: 4 gate-tiles x 5 K-tiles, bias as C-init ----
        f4v acc[4];
        #pragma unroll
        for (int G = 0; G < 4; ++G)
            acc[G] = __builtin_amdgcn_mfma_f32_16x16x32_f16(A[G][0], Bf0, biasv[G], 0, 0, 0);
        #pragma unroll
        for (int G = 0; G < 4; ++G)
            acc[G] = __builtin_amdgcn_mfma_f32_16x16x32_f16(A[G][1], Bf1, acc[G], 0, 0, 0);
        #pragma unroll
        for (int G = 0; G < 4; ++G)
            acc[G] = __builtin_amdgcn_mfma_f32_16x16x32_f16(A[G][2], Bf2, acc[G], 0, 0, 0);
        #pragma unroll
        for (int G = 0; G < 4; ++G)
            acc[G] = __builtin_amdgcn_mfma_f32_16x16x32_f16(A[G][3], Bf3, acc[G], 0, 0, 0);
        #pragma unroll
        for (int G = 0; G < 4; ++G)
            acc[G] = __builtin_amdgcn_mfma_f32_16x16x32_f16(A[G][4], bxf, acc[G], 0, 0, 0);

        // ---- activation: 4 units per lane (i,f,g,o in acc[0..3][r]) ----
        float hv[4];
        #pragma unroll
        for (int r = 0; r < 4; ++r) {
            const float gi = sigf(acc[0][r]);
            const float gf = sigf(acc[1][r]);
            const float gg = tanh_f(acc[2][r]);
            const float go = sigf(acc[3][r]);
            cc[r] = fmaf(gf, cc[r], gi * gg);
            hv[r] = go * tanh_f(cc[r]);
        }

        // publish h_t fragment: 4 f16, +8n rotated columns, one b64 write
        h4v hp = (h4v){(_Float16)hv[0], (_Float16)hv[1],
                       (_Float16)hv[2], (_Float16)hv[3]};
        *(h4v*)&Hlds[par ^ 1][n][(j0 + 8 * n) & 127] = hp;

        // ---- fused FC: partial over 4 units, reduce xor16 (swz) + xor32 ----
        float p0 = 0.f, p1 = 0.f, p2 = 0.f;
        #pragma unroll
        for (int r = 0; r < 4; ++r) {
            p0 = fmaf(wfc0[r], hv[r], p0);
            p1 = fmaf(wfc1[r], hv[r], p1);
            p2 = fmaf(wfc2[r], hv[r], p2);
        }
        p0 += SWZF(p0, 0x401F);
        p1 += SWZF(p1, 0x401F);
        p2 += SWZF(p2, 0x401F);
        p0 = xor32_add(p0);
        p1 = xor32_add(p1);
        p2 = xor32_add(p2);
        pp0 = p0; pp1 = p1; pp2 = p2;
        pid = idn;

        lds_barrier();   // single barrier per step (H double-buffered)
    }

    // flush the final step's pipelined contribution
    if (lane < NB && (unsigned)pid < (unsigned)P_) {
        atomicAdd(&sums_lds[lane][pid * O_ + 0], pp0);
        atomicAdd(&sums_lds[lane][pid * O_ + 1], pp1);
        atomicAdd(&sums_lds[lane][pid * O_ + 2], pp2);
        if (w == 0) atomicAdd(&counts_lds[lane][pid], 1.f);
    }
    __syncthreads();

    // ---- writeback (block owns batches [NB*bx, NB*bx+NB) exclusively) ----
    float* sums_g = sums + (size_t)(NB * bx) * P_ * O_;
    for (int i = tid; i < NB * P_ * O_; i += 512)
        sums_g[i] = ((const float*)sums_lds)[i];
    float* cnt_g = counts + (size_t)(NB * bx) * P_;
    for (int i = tid; i < NB * P_; i += 512)
        cnt_g[i] = ((const float*)counts_lds)[i];
}

// out[b,p,o] = (sums[b,p,o] + cnt*b_fc[o]) / max(cnt,1)
__global__ void finalize_kernel(const float* __restrict__ sums,
                                const float* __restrict__ counts,
                                const float* __restrict__ b_fc,
                                float* __restrict__ out)
{
    const int idx = blockIdx.x * blockDim.x + threadIdx.x;
    if (idx >= B_ * P_ * O_) return;
    const int o  = idx % O_;
    const int bp = idx / O_;
    const float cnt = counts[bp];
    const float denom = (cnt > 0.f) ? cnt : 1.f;
    out[idx] = (sums[idx] + cnt * b_fc[o]) / denom;
}

extern "C" void kernel_launch(void* const* d_in, const int* in_sizes, int n_in,
                              void* d_out, int out_size, void* d_ws, size_t ws_size,
                              hipStream_t stream) {
    const float* x    = (const float*)d_in[0];
    const float* W_ih = (const float*)d_in[1];
    const float* W_hh = (const float*)d_in[2];
    const float* b_ih = (const float*)d_in[3];
    const float* b_hh = (const float*)d_in[4];
    const float* W_fc = (const float*)d_in[5];
    const float* b_fc = (const float*)d_in[6];
    // d_in[7] = num_photos (==P_, fixed by the problem)

    float* out    = (float*)d_out;
    float* sums   = (float*)d_ws;                 // B*P*3 floats
    float* counts = sums + (size_t)B_ * P_ * O_;  // B*P floats
    // sums/counts fully overwritten by lstm_fused — no memset needed.

    lstm_fused<<<BLOCKS, 512, 0, stream>>>(x, W_ih, W_hh, b_ih, b_hh, W_fc,
                                           sums, counts);

    const int n = B_ * P_ * O_;
    finalize_kernel<<<(n + 255) / 256, 256, 0, stream>>>(sums, counts, b_fc, out);
}

// Round 8
// 6550.932 us; speedup vs baseline: 2.1652x; 2.1652x over previous
//
#include <hip/hip_runtime.h>

// Problem constants (fixed by reference setup)
#define B_ 32
#define T_ 8192
#define I_ 16
#define H_ 128
#define P_ 1024
#define O_ 3

// R13: back to the R6 512-thread skeleton (best passing: 6055 us), with the
// dot phase moved from v_dot2_f32_f16 to plain v_fma_f32 on fp32 weights.
// Seven-round model fit: dot2/fma_mix are half-rate-or-worse (4-8cy/instr),
// plain VALU is full-rate 2cy (m07: 103 TF), and >=2 waves/SIMD are needed
// to saturate issue (single-wave caps at ~1 instr/4cy — R7/R10/R11).
// R6 was exactly issue-bound (2 waves x 876cy = 1752 ~ measured 1760), so
// the only lever left in this structure is cycles-per-MAC: 288 fma@2cy vs
// 144 dot2@4-8cy. Discriminating experiment: dot2=4 => neutral; dot2>=6 =>
// -20-30%. Cannot regress materially; correctness surface unchanged.
// f32 h/x in LDS (19 KB total); weights 144 f32 VGPRs (cap 256 at 2 w/EU).

// DPP (quad_perm / row_ror): pure-VALU cross-lane, no LDS round-trip.
#define DPPF(v, ctrl) \
    __int_as_float(__builtin_amdgcn_mov_dpp(__float_as_int(v), (ctrl), 0xF, 0xF, true))

// xor32-add via gfx950 v_permlane32_swap_b32 (pure VALU).
__device__ __forceinline__ float xor32_add(float p) {
    float a = p, b = p;
    asm("v_permlane32_swap_b32 %0, %1" : "+v"(a), "+v"(b));
    return a + b;
}

__device__ __forceinline__ float tanh_f(float x) {
    return 2.f / (1.f + __expf(-2.f * x)) - 1.f;
}

// LDS-only barrier: drain DS ops + s_barrier, without __syncthreads' vmcnt(0)
// drain (x-prefetch loads are consumed via register dependency).
__device__ __forceinline__ void lds_barrier() {
    asm volatile("s_waitcnt lgkmcnt(0)\n\ts_barrier" ::: "memory");
}

#define FMA4(acc, hv, wv) \
    acc = fmaf((hv).x, (wv).x, acc); acc = fmaf((hv).y, (wv).y, acc); \
    acc = fmaf((hv).z, (wv).z, acc); acc = fmaf((hv).w, (wv).w, acc);

// One block per batch element. 512 threads, thread = (j, kc): j=unit 0..127,
// kc=quad lane 0..3. Thread covers 4 gate rows {g*128+j} x the f32 h-subset
// {kc*8+32m+e : m=0..3, e=0..7} (broadcast/conflict-free b128 reads).
// fp32 weights in named float4 scalars (144 VGPRs). c fp32. Single
// lds_barrier per step; VALU-only FC reduce; atomics pipelined one step.
__global__ __launch_bounds__(512, 2) __attribute__((amdgpu_waves_per_eu(2, 2)))
void lstm_fused(
    const float* __restrict__ x,      // [B,T,16]
    const float* __restrict__ W_ih,   // [512,16]
    const float* __restrict__ W_hh,   // [512,128]
    const float* __restrict__ b_ih,   // [512]
    const float* __restrict__ b_hh,   // [512]
    const float* __restrict__ W_fc,   // [3,128]
    float* __restrict__ sums,         // [B,P,3]  (fully overwritten per block)
    float* __restrict__ counts)       // [B,P]    (fully overwritten per block)
{
    const int b   = blockIdx.x;
    const int tid = threadIdx.x;
    const int j   = tid >> 2;
    const int kc  = tid & 3;

    __shared__ __align__(16) float hh[2][H_];       // hidden state, f32 (1 KB)
    __shared__ __align__(16) float xt[2][16 * I_];  // x tile, f32 (2 KB)
    __shared__ float sums_lds[P_ * O_];             // 12 KB
    __shared__ float counts_lds[P_];                // 4 KB

    // ---- weights -> f32 float4 named scalars (32+4 = 36 float4 = 144 VGPR) ----
    const float* wr0 = W_hh + (0 * H_ + j) * H_;
    const float* wr1 = W_hh + (1 * H_ + j) * H_;
    const float* wr2 = W_hh + (2 * H_ + j) * H_;
    const float* wr3 = W_hh + (3 * H_ + j) * H_;
    // slot (g,m) holds W_hh[g*128+j][kc*8+32m .. +7] as two float4
    #define WLOAD(g, m) \
        const float4 W##g##_##m##_l = *(const float4*)(wr##g + kc * 8 + 32 * (m)); \
        const float4 W##g##_##m##_h = *(const float4*)(wr##g + kc * 8 + 32 * (m) + 4);
    WLOAD(0,0) WLOAD(0,1) WLOAD(0,2) WLOAD(0,3)
    WLOAD(1,0) WLOAD(1,1) WLOAD(1,2) WLOAD(1,3)
    WLOAD(2,0) WLOAD(2,1) WLOAD(2,2) WLOAD(2,3)
    WLOAD(3,0) WLOAD(3,1) WLOAD(3,2) WLOAD(3,3)

    // W_ih: gate g, x-chunk [kc*4, kc*4+4) as one float4
    const float4 U0 = *(const float4*)(W_ih + (0 * H_ + j) * I_ + kc * 4);
    const float4 U1 = *(const float4*)(W_ih + (1 * H_ + j) * I_ + kc * 4);
    const float4 U2 = *(const float4*)(W_ih + (2 * H_ + j) * I_ + kc * 4);
    const float4 U3 = *(const float4*)(W_ih + (3 * H_ + j) * I_ + kc * 4);

    // lane kc activates gate kc: its own row is kc*128+j
    const float bias = b_ih[kc * H_ + j] + b_hh[kc * H_ + j];
    const float wfc  = (kc < 3) ? W_fc[kc * H_ + j] : 0.f;

    // FC atomic lanes: reduce covers lane-xor {4,8,32} (row_ror x2 +
    // permlane32); remaining xor16 handled by 2-way same-address atomic from
    // lanes {kc, 16+kc}. Mask bits 2,3,5 of the lane id.
    const bool fc_lane = ((tid & 0x2C) == 0) && (kc < 3);

    // ---- init LDS ----
    for (int i = tid; i < P_ * O_; i += 512) sums_lds[i] = 0.f;
    for (int i = tid; i < P_;      i += 512) counts_lds[i] = 0.f;
    if (tid < H_) hh[0][tid] = 0.f;

    const float* xb = x + (size_t)b * T_ * I_;
    float4 xr4 = make_float4(0.f, 0.f, 0.f, 0.f);
    if (tid < 64) {                       // tile 0 = steps 0..15
        xr4 = ((const float4*)xb)[tid];
        *(float4*)&xt[0][tid * 4] = xr4;
    }
    float c = 0.f;
    float pend_p = 0.f;   // pipelined FC partial (from step t-1)
    int   pend_id = 0;
    __syncthreads();

    #pragma unroll 1
    for (int t = 0; t < T_; ++t) {
        const int off = t & 15;
        const int btx = (t >> 4) & 1;
        const int bh  = t & 1;

        // ---- pipelined FC/count atomics from step t-1 (off the critical
        // path: complete during the fma phase, long done by the barrier).
        if (t != 0) {
            if (fc_lane && (unsigned)pend_id < (unsigned)P_)
                atomicAdd(&sums_lds[pend_id * O_ + kc], pend_p);
            if (tid == 0 && (unsigned)pend_id < (unsigned)P_)
                atomicAdd(&counts_lds[pend_id], 1.f);
        }

        // x prefetch (wave 0): issue tile t+16 at off==0, commit at off==8
        if (tid < 64) {
            if (off == 0 && t + 16 < T_)
                xr4 = ((const float4*)(xb + (t + 16) * I_))[tid];
            if (off == 8 && t + 8 < T_)
                *(float4*)&xt[btx ^ 1][tid * 4] = xr4;
        }

        const float4 xv = *(const float4*)&xt[btx][off * I_ + kc * 4];
        const int id = (int)xt[btx][off * I_ + 2];          // exact (id<2048)

        // 4 gate-row partials over this thread's 32-float h subset, fp32 fma
        // (full-rate pipe). Broadcast/conflict-free b128 reads (addr depends
        // only on kc: 4 addrs x 4 banks = 16 banks).
        float acc0 = 0.f, acc1 = 0.f, acc2 = 0.f, acc3 = 0.f;
        #define HD(m) { \
            const float4 hl = *(const float4*)&hh[bh][kc * 8 + 32 * (m)]; \
            const float4 hu = *(const float4*)&hh[bh][kc * 8 + 32 * (m) + 4]; \
            FMA4(acc0, hl, W0_##m##_l) FMA4(acc0, hu, W0_##m##_h) \
            FMA4(acc1, hl, W1_##m##_l) FMA4(acc1, hu, W1_##m##_h) \
            FMA4(acc2, hl, W2_##m##_l) FMA4(acc2, hu, W2_##m##_h) \
            FMA4(acc3, hl, W3_##m##_l) FMA4(acc3, hu, W3_##m##_h) }
        HD(0) HD(1) HD(2) HD(3)
        // x contribution
        FMA4(acc0, xv, U0)
        FMA4(acc1, xv, U1)
        FMA4(acc2, xv, U2)
        FMA4(acc3, xv, U3)

        // quad butterfly (xor1=0xB1, xor2=0x4E): all 4 lanes get all 4 totals
        float s_;
        s_ = DPPF(acc0, 0xB1); acc0 += s_;
        s_ = DPPF(acc1, 0xB1); acc1 += s_;
        s_ = DPPF(acc2, 0xB1); acc2 += s_;
        s_ = DPPF(acc3, 0xB1); acc3 += s_;
        s_ = DPPF(acc0, 0x4E); acc0 += s_;
        s_ = DPPF(acc1, 0x4E); acc1 += s_;
        s_ = DPPF(acc2, 0x4E); acc2 += s_;
        s_ = DPPF(acc3, 0x4E); acc3 += s_;

        // lane kc activates gate kc (i,f,o sigmoid; g=kc==2 tanh), branchless
        float tg = (kc == 0) ? acc0 : (kc == 1) ? acc1 : (kc == 2) ? acc2 : acc3;
        tg += bias;
        const bool  isg = (kc == 2);
        const float arg = isg ? (tg + tg) : tg;
        const float sf  = 1.f / (1.f + __expf(-arg));
        const float act = isg ? (sf + sf - 1.f) : sf;   // tanh = 2*sig(2x)-1

        // gather the quad's 4 activated gates (quad_perm broadcasts)
        const float gi = DPPF(act, 0x00);
        const float gf = DPPF(act, 0x55);
        const float gg = DPPF(act, 0xAA);
        const float go = DPPF(act, 0xFF);
        c = fmaf(gf, c, gi * gg);            // c replicated across the quad
        const float hnew = go * tanh_f(c);

        if (kc == 0) hh[bh ^ 1][j] = hnew;   // publish h_t (f32, 16 banks/wave)

        // fused FC partial: VALU-only wave reduce (row_ror:4 + row_ror:8 +
        // permlane32_swap); xor16 left for the 2-way same-address atomic.
        float p = hnew * wfc;
        p += DPPF(p, 0x124);
        p += DPPF(p, 0x128);
        p = xor32_add(p);
        pend_p  = p;
        pend_id = id;

        lds_barrier();   // single barrier per step (h double-buffered)
    }

    // flush the final step's pipelined contribution
    if (fc_lane && (unsigned)pend_id < (unsigned)P_)
        atomicAdd(&sums_lds[pend_id * O_ + kc], pend_p);
    if (tid == 0 && (unsigned)pend_id < (unsigned)P_)
        atomicAdd(&counts_lds[pend_id], 1.f);
    __syncthreads();

    // ---- writeback (block b owns slice b exclusively) ----
    float* sums_g = sums + (size_t)b * P_ * O_;
    for (int i = tid; i < P_ * O_; i += 512) sums_g[i] = sums_lds[i];
    float* cnt_g = counts + (size_t)b * P_;
    for (int i = tid; i < P_; i += 512) cnt_g[i] = counts_lds[i];
}

// out[b,p,o] = (sums[b,p,o] + cnt*b_fc[o]) / max(cnt,1)
__global__ void finalize_kernel(const float* __restrict__ sums,
                                const float* __restrict__ counts,
                                const float* __restrict__ b_fc,
                                float* __restrict__ out)
{
    const int idx = blockIdx.x * blockDim.x + threadIdx.x;
    if (idx >= B_ * P_ * O_) return;
    const int o  = idx % O_;
    const int bp = idx / O_;
    const float cnt = counts[bp];
    const float denom = (cnt > 0.f) ? cnt : 1.f;
    out[idx] = (sums[idx] + cnt * b_fc[o]) / denom;
}

extern "C" void kernel_launch(void* const* d_in, const int* in_sizes, int n_in,
                              void* d_out, int out_size, void* d_ws, size_t ws_size,
                              hipStream_t stream) {
    const float* x    = (const float*)d_in[0];
    const float* W_ih = (const float*)d_in[1];
    const float* W_hh = (const float*)d_in[2];
    const float* b_ih = (const float*)d_in[3];
    const float* b_hh = (const float*)d_in[4];
    const float* W_fc = (const float*)d_in[5];
    const float* b_fc = (const float*)d_in[6];
    // d_in[7] = num_photos (==P_, fixed by the problem)

    float* out    = (float*)d_out;
    float* sums   = (float*)d_ws;                 // B*P*3 floats
    float* counts = sums + (size_t)B_ * P_ * O_;  // B*P floats
    // sums/counts fully overwritten by lstm_fused — no memset needed.

    lstm_fused<<<B_, 512, 0, stream>>>(x, W_ih, W_hh, b_ih, b_hh, W_fc,
                                       sums, counts);

    const int n = B_ * P_ * O_;
    finalize_kernel<<<(n + 255) / 256, 256, 0, stream>>>(sums, counts, b_fc, out);
}

// Round 9
// 6412.469 us; speedup vs baseline: 2.2120x; 1.0216x over previous
//
#include <hip/hip_runtime.h>

// Problem constants (fixed by reference setup)
#define B_ 32
#define T_ 8192
#define I_ 16
#define H_ 128
#define P_ 1024
#define O_ 3

typedef _Float16 h2 __attribute__((ext_vector_type(2)));
typedef _Float16 h4 __attribute__((ext_vector_type(4)));
typedef _Float16 h8 __attribute__((ext_vector_type(8)));

// R14: v_pk_fma_f16 — the VERTICAL packed f16 MAC (2 MACs / 2 cy, the only
// op implied by the 2x-f16 vector spec rate). 8-round fit: dot2 (horizontal)
// = 4cy, fma_mix = 4cy+, plain fma_f32 = 2cy — all capped at 1 MAC/2cy.
// pk_fma_f16 is the remaining candidate for 2 MACs/2cy. Each packed half
// accumulates only 18 f16 terms (~3e-4 extra err vs 7.8e-3 threshold), then
// converts to f32 before the quad butterfly. Base: R6 512-thread kernel
// (passed at 6055 us) with ONLY the accumulator type changed.
#if __has_builtin(__builtin_elementwise_fma)
#define PKFMA(a, b, c) __builtin_elementwise_fma((a), (b), (c))
#else
__device__ __forceinline__ h2 pkfma_asm(h2 a, h2 b, h2 c) {
    asm("v_pk_fma_f16 %0, %1, %2, %0" : "+v"(c) : "v"(a), "v"(b));
    return c;
}
#define PKFMA(a, b, c) pkfma_asm((a), (b), (c))
#endif

// ---- macro machinery: (gate g 0..3, m 0..3, e 0..3) ------------------------
#define FORME(M, g) M(g,0,0) M(g,0,1) M(g,0,2) M(g,0,3) \
                    M(g,1,0) M(g,1,1) M(g,1,2) M(g,1,3) \
                    M(g,2,0) M(g,2,1) M(g,2,2) M(g,2,3) \
                    M(g,3,0) M(g,3,1) M(g,3,2) M(g,3,3)
#define FORALL(M) FORME(M,0) FORME(M,1) FORME(M,2) FORME(M,3)
#define FORG(M) M(0) M(1) M(2) M(3)

// DPP (quad_perm / row_ror): pure-VALU cross-lane, no LDS round-trip.
#define DPPF(v, ctrl) \
    __int_as_float(__builtin_amdgcn_mov_dpp(__float_as_int(v), (ctrl), 0xF, 0xF, true))

// xor32-add via gfx950 v_permlane32_swap_b32 (pure VALU).
__device__ __forceinline__ float xor32_add(float p) {
    float a = p, b = p;
    asm("v_permlane32_swap_b32 %0, %1" : "+v"(a), "+v"(b));
    return a + b;
}

__device__ __forceinline__ float tanh_f(float x) {
    return 2.f / (1.f + __expf(-2.f * x)) - 1.f;
}
__device__ __forceinline__ h4 cvt4(float4 v) {
    return (h4){(_Float16)v.x, (_Float16)v.y, (_Float16)v.z, (_Float16)v.w};
}

// LDS-only barrier: drain DS ops + s_barrier, without __syncthreads' vmcnt(0)
// drain (x-prefetch loads are consumed via register dependency).
__device__ __forceinline__ void lds_barrier() {
    asm volatile("s_waitcnt lgkmcnt(0)\n\ts_barrier" ::: "memory");
}

// One block per batch element. 512 threads, thread = (j, kc): j=unit 0..127,
// kc=quad lane 0..3. Thread covers 4 gate rows {g*128+j} x the f16 h-subset
// {kc*8+32m+e : m=0..3, e=0..7} (broadcast/conflict-free ds_read_b128s).
// Weights as f16 half2 named scalars; packed-f16 accumulation (pk_fma),
// f32 combine before the butterfly; cell state c fp32. Single lds_barrier
// per step; VALU-only FC reduce; atomics pipelined one step.
__global__ __launch_bounds__(512, 2) __attribute__((amdgpu_waves_per_eu(2, 2)))
void lstm_fused(
    const float* __restrict__ x,      // [B,T,16]
    const float* __restrict__ W_ih,   // [512,16]
    const float* __restrict__ W_hh,   // [512,128]
    const float* __restrict__ b_ih,   // [512]
    const float* __restrict__ b_hh,   // [512]
    const float* __restrict__ W_fc,   // [3,128]
    float* __restrict__ sums,         // [B,P,3]  (fully overwritten per block)
    float* __restrict__ counts)       // [B,P]    (fully overwritten per block)
{
    const int b   = blockIdx.x;
    const int tid = threadIdx.x;
    const int j   = tid >> 2;
    const int kc  = tid & 3;

    __shared__ __align__(16) _Float16 hh[2][H_];       // hidden state, f16
    __shared__ __align__(16) _Float16 xt[2][16 * I_];  // x tile, f16
    __shared__ float sums_lds[P_ * O_];                // 12 KB
    __shared__ float counts_lds[P_];                   // 4 KB

    // ---- weights -> f16 half2 named scalars (64 + 8 = 72 VGPRs) ----
    const float* wr0 = W_hh + (0 * H_ + j) * H_;
    const float* wr1 = W_hh + (1 * H_ + j) * H_;
    const float* wr2 = W_hh + (2 * H_ + j) * H_;
    const float* wr3 = W_hh + (3 * H_ + j) * H_;
    // slot (g,m,e) holds W_hh[g*128+j][kc*8+32m+2e .. +1]
    #define WLOAD(g, m, e) h2 W##g##_##m##_##e = (h2){ \
        (_Float16)wr##g[kc * 8 + 32 * (m) + 2 * (e)], \
        (_Float16)wr##g[kc * 8 + 32 * (m) + 2 * (e) + 1]};
    FORALL(WLOAD)

    // W_ih: gate g, x-chunk [kc*4, kc*4+4) as 2 half2
    #define ULOAD(g) \
        h2 U##g##_0 = (h2){(_Float16)W_ih[((g) * H_ + j) * I_ + kc * 4 + 0], \
                           (_Float16)W_ih[((g) * H_ + j) * I_ + kc * 4 + 1]}; \
        h2 U##g##_1 = (h2){(_Float16)W_ih[((g) * H_ + j) * I_ + kc * 4 + 2], \
                           (_Float16)W_ih[((g) * H_ + j) * I_ + kc * 4 + 3]};
    FORG(ULOAD)

    // lane kc activates gate kc: its own row is kc*128+j
    const float bias = b_ih[kc * H_ + j] + b_hh[kc * H_ + j];
    const float wfc  = (kc < 3) ? W_fc[kc * H_ + j] : 0.f;

    // FC atomic lanes: reduce covers lane-xor {4,8,32} (row_ror x2 +
    // permlane32); remaining xor16 handled by 2-way same-address atomic from
    // lanes {kc, 16+kc}. Mask bits 2,3,5 of the lane id.
    const bool fc_lane = ((tid & 0x2C) == 0) && (kc < 3);

    // ---- init LDS ----
    for (int i = tid; i < P_ * O_; i += 512) sums_lds[i] = 0.f;
    for (int i = tid; i < P_;      i += 512) counts_lds[i] = 0.f;
    if (tid < H_) hh[0][tid] = (_Float16)0.f;

    const float* xb = x + (size_t)b * T_ * I_;
    float4 xr4 = make_float4(0.f, 0.f, 0.f, 0.f);
    if (tid < 64) {                       // tile 0 = steps 0..15
        xr4 = ((const float4*)xb)[tid];
        *(h4*)&xt[0][tid * 4] = cvt4(xr4);
    }
    float c = 0.f;
    float pend_p = 0.f;   // pipelined FC partial (from step t-1)
    int   pend_id = 0;
    __syncthreads();

    #pragma unroll 1
    for (int t = 0; t < T_; ++t) {
        const int off = t & 15;
        const int btx = (t >> 4) & 1;
        const int bh  = t & 1;

        // ---- pipelined FC/count atomics from step t-1 (off the critical
        // path: complete during the dot phase, long done by the barrier).
        if (t != 0) {
            if (fc_lane && (unsigned)pend_id < (unsigned)P_)
                atomicAdd(&sums_lds[pend_id * O_ + kc], pend_p);
            if (tid == 0 && (unsigned)pend_id < (unsigned)P_)
                atomicAdd(&counts_lds[pend_id], 1.f);
        }

        // x prefetch (wave 0): issue tile t+16 at off==0, commit at off==8
        if (tid < 64) {
            if (off == 0 && t + 16 < T_)
                xr4 = ((const float4*)(xb + (t + 16) * I_))[tid];
            if (off == 8 && t + 8 < T_)
                *(h4*)&xt[btx ^ 1][tid * 4] = cvt4(xr4);
        }

        // x/id reads at the top: their LDS latency pipelines under the h
        // ds_read_b128 latency shadow.
        const h4 xv4 = *(const h4*)&xt[btx][off * I_ + kc * 4];
        const h2 xv0 = __builtin_shufflevector(xv4, xv4, 0, 1);
        const h2 xv1 = __builtin_shufflevector(xv4, xv4, 2, 3);
        const int id = (int)(float)xt[btx][off * I_ + 2];   // exact (id<2048)

        // 4 gate-row partials over this thread's 32-float h subset:
        // packed-f16 fma (v_pk_fma_f16, 2 MACs/2cy). Each packed half
        // accumulates 18 terms max -> f16-safe; combined to f32 below.
        h2 pk0 = (h2){(_Float16)0.f, (_Float16)0.f};
        h2 pk1 = pk0, pk2 = pk0, pk3 = pk0;
        #define HD(m) { \
            h8 hv = *(const h8*)&hh[bh][kc * 8 + 32 * (m)]; \
            h2 p0 = __builtin_shufflevector(hv, hv, 0, 1); \
            h2 p1 = __builtin_shufflevector(hv, hv, 2, 3); \
            h2 p2 = __builtin_shufflevector(hv, hv, 4, 5); \
            h2 p3 = __builtin_shufflevector(hv, hv, 6, 7); \
            pk0 = PKFMA(p0, W0_##m##_0, pk0); pk0 = PKFMA(p1, W0_##m##_1, pk0); \
            pk0 = PKFMA(p2, W0_##m##_2, pk0); pk0 = PKFMA(p3, W0_##m##_3, pk0); \
            pk1 = PKFMA(p0, W1_##m##_0, pk1); pk1 = PKFMA(p1, W1_##m##_1, pk1); \
            pk1 = PKFMA(p2, W1_##m##_2, pk1); pk1 = PKFMA(p3, W1_##m##_3, pk1); \
            pk2 = PKFMA(p0, W2_##m##_0, pk2); pk2 = PKFMA(p1, W2_##m##_1, pk2); \
            pk2 = PKFMA(p2, W2_##m##_2, pk2); pk2 = PKFMA(p3, W2_##m##_3, pk2); \
            pk3 = PKFMA(p0, W3_##m##_0, pk3); pk3 = PKFMA(p1, W3_##m##_1, pk3); \
            pk3 = PKFMA(p2, W3_##m##_2, pk3); pk3 = PKFMA(p3, W3_##m##_3, pk3); }
        HD(0) HD(1) HD(2) HD(3)
        // x contribution (packed)
        pk0 = PKFMA(xv0, U0_0, pk0); pk0 = PKFMA(xv1, U0_1, pk0);
        pk1 = PKFMA(xv0, U1_0, pk1); pk1 = PKFMA(xv1, U1_1, pk1);
        pk2 = PKFMA(xv0, U2_0, pk2); pk2 = PKFMA(xv1, U2_1, pk2);
        pk3 = PKFMA(xv0, U3_0, pk3); pk3 = PKFMA(xv1, U3_1, pk3);

        // combine packed halves in f32
        float acc0 = (float)pk0.x + (float)pk0.y;
        float acc1 = (float)pk1.x + (float)pk1.y;
        float acc2 = (float)pk2.x + (float)pk2.y;
        float acc3 = (float)pk3.x + (float)pk3.y;

        // quad butterfly (xor1=0xB1, xor2=0x4E): all 4 lanes get all 4 totals
        float s_;
        s_ = DPPF(acc0, 0xB1); acc0 += s_;
        s_ = DPPF(acc1, 0xB1); acc1 += s_;
        s_ = DPPF(acc2, 0xB1); acc2 += s_;
        s_ = DPPF(acc3, 0xB1); acc3 += s_;
        s_ = DPPF(acc0, 0x4E); acc0 += s_;
        s_ = DPPF(acc1, 0x4E); acc1 += s_;
        s_ = DPPF(acc2, 0x4E); acc2 += s_;
        s_ = DPPF(acc3, 0x4E); acc3 += s_;

        // lane kc activates gate kc (i,f,o sigmoid; g=kc==2 tanh), branchless
        float tg = (kc == 0) ? acc0 : (kc == 1) ? acc1 : (kc == 2) ? acc2 : acc3;
        tg += bias;
        const bool  isg = (kc == 2);
        const float arg = isg ? (tg + tg) : tg;
        const float sf  = 1.f / (1.f + __expf(-arg));
        const float act = isg ? (sf + sf - 1.f) : sf;   // tanh = 2*sig(2x)-1

        // gather the quad's 4 activated gates (quad_perm broadcasts)
        const float gi = DPPF(act, 0x00);
        const float gf = DPPF(act, 0x55);
        const float gg = DPPF(act, 0xAA);
        const float go = DPPF(act, 0xFF);
        c = fmaf(gf, c, gi * gg);            // c replicated across the quad (fp32)
        const float hnew = go * tanh_f(c);

        if (kc == 0) hh[bh ^ 1][j] = (_Float16)hnew;   // publish h_t (f16)

        // fused FC partial: VALU-only wave reduce (row_ror:4 + row_ror:8 +
        // permlane32_swap); xor16 left for the 2-way same-address atomic.
        float p = hnew * wfc;
        p += DPPF(p, 0x124);
        p += DPPF(p, 0x128);
        p = xor32_add(p);
        pend_p  = p;
        pend_id = id;

        lds_barrier();   // single barrier per step (h double-buffered)
    }

    // flush the final step's pipelined contribution
    if (fc_lane && (unsigned)pend_id < (unsigned)P_)
        atomicAdd(&sums_lds[pend_id * O_ + kc], pend_p);
    if (tid == 0 && (unsigned)pend_id < (unsigned)P_)
        atomicAdd(&counts_lds[pend_id], 1.f);
    __syncthreads();

    // ---- writeback (block b owns slice b exclusively) ----
    float* sums_g = sums + (size_t)b * P_ * O_;
    for (int i = tid; i < P_ * O_; i += 512) sums_g[i] = sums_lds[i];
    float* cnt_g = counts + (size_t)b * P_;
    for (int i = tid; i < P_; i += 512) cnt_g[i] = counts_lds[i];
}

// out[b,p,o] = (sums[b,p,o] + cnt*b_fc[o]) / max(cnt,1)
__global__ void finalize_kernel(const float* __restrict__ sums,
                                const float* __restrict__ counts,
                                const float* __restrict__ b_fc,
                                float* __restrict__ out)
{
    const int idx = blockIdx.x * blockDim.x + threadIdx.x;
    if (idx >= B_ * P_ * O_) return;
    const int o  = idx % O_;
    const int bp = idx / O_;
    const float cnt = counts[bp];
    const float denom = (cnt > 0.f) ? cnt : 1.f;
    out[idx] = (sums[idx] + cnt * b_fc[o]) / denom;
}

extern "C" void kernel_launch(void* const* d_in, const int* in_sizes, int n_in,
                              void* d_out, int out_size, void* d_ws, size_t ws_size,
                              hipStream_t stream) {
    const float* x    = (const float*)d_in[0];
    const float* W_ih = (const float*)d_in[1];
    const float* W_hh = (const float*)d_in[2];
    const float* b_ih = (const float*)d_in[3];
    const float* b_hh = (const float*)d_in[4];
    const float* W_fc = (const float*)d_in[5];
    const float* b_fc = (const float*)d_in[6];
    // d_in[7] = num_photos (==P_, fixed by the problem)

    float* out    = (float*)d_out;
    float* sums   = (float*)d_ws;                 // B*P*3 floats
    float* counts = sums + (size_t)B_ * P_ * O_;  // B*P floats
    // sums/counts fully overwritten by lstm_fused — no memset needed.

    lstm_fused<<<B_, 512, 0, stream>>>(x, W_ih, W_hh, b_ih, b_hh, W_fc,
                                       sums, counts);

    const int n = B_ * P_ * O_;
    finalize_kernel<<<(n + 255) / 256, 256, 0, stream>>>(sums, counts, b_fc, out);
}